// Round 4
// baseline (240.012 us; speedup 1.0000x reference)
//
#include <hip/hip_runtime.h>

#define BB 32
#define LL 1024
#define HH 384
#define H4 (HH / 4)    // 96 float4 per row
#define TT 128         // t-positions per block
#define NT 256         // threads per block (4 waves)

typedef float f32x4 __attribute__((ext_vector_type(4)));

__global__ __launch_bounds__(NT) void lenreg_kernel(
    const float* __restrict__ ehs,   // (B, L, H) f32
    const int* __restrict__ dur,     // (B, L) i32
    float* __restrict__ out,         // (B, T, H) f32
    float* __restrict__ mask,        // (B, T) f32
    int T)
{
    __shared__ int scum[LL];     // inclusive cumsum of durations[b,:]
    __shared__ int wsum[4];      // per-wave totals
    __shared__ int sidx[TT];     // source token index per t in this tile

    const int tid  = threadIdx.x;
    const int lane = tid & 63;
    const int wav  = tid >> 6;
    const int b    = blockIdx.y;
    const int t0   = blockIdx.x * TT;

    // ---- cumsum of durations[b,:] via wave-shuffle scan (2 barriers) ----
    int4 d = ((const int4*)(dur + (size_t)b * LL))[tid];
    const int p0 = d.x;
    const int p1 = p0 + d.y;
    const int p2 = p1 + d.z;
    const int p3 = p2 + d.w;

    // inclusive scan of p3 across the 64-lane wave
    int v = p3;
    #pragma unroll
    for (int off = 1; off < 64; off <<= 1) {
        const int u = __shfl_up(v, off, 64);
        if (lane >= off) v += u;
    }
    if (lane == 63) wsum[wav] = v;
    __syncthreads();
    // add preceding-wave totals (4 entries, broadcast reads)
    int woff = 0;
    #pragma unroll
    for (int i = 0; i < 3; ++i) {
        if (i < wav) woff += wsum[i];
    }
    const int excl = woff + v - p3;   // exclusive prefix for this thread's 4 elems
    scum[4 * tid + 0] = excl + p0;
    scum[4 * tid + 1] = excl + p1;
    scum[4 * tid + 2] = excl + p2;
    scum[4 * tid + 3] = excl + p3;
    __syncthreads();

    const int total = scum[LL - 1];

    // ---- binary search: idx[t] = #(cum <= t), clamp L-1 (side='right') ----
    if (tid < TT) {
        const int t = t0 + tid;
        int lo = 0, hi = LL;
        while (lo < hi) {
            const int mid = (lo + hi) >> 1;
            if (scum[mid] <= t) lo = mid + 1; else hi = mid;
        }
        sidx[tid] = (lo < LL - 1) ? lo : (LL - 1);
        if (t < T) {
            const float mv = (t < total) ? 1.0f : 0.0f;
            __builtin_nontemporal_store(mv, mask + (size_t)b * T + t);
        }
    }
    __syncthreads();

    // ---- gather + nontemporal store: TT rows x 96 float4, coalesced ----
    const f32x4* __restrict__ src_base = (const f32x4*)(ehs + (size_t)b * LL * HH);
    f32x4* __restrict__ out4 = (f32x4*)out;
    const f32x4 zero4 = (f32x4){0.f, 0.f, 0.f, 0.f};

    for (int w = tid; w < TT * H4; w += NT) {
        const int tl = w / H4;          // const-div -> magic mul
        const int vv = w - tl * H4;
        const int t  = t0 + tl;
        if (t >= T) break;              // t non-decreasing in w per thread
        f32x4 val = zero4;
        if (t < total) {
            val = src_base[(size_t)sidx[tl] * H4 + vv];
        }
        __builtin_nontemporal_store(val, &out4[((size_t)b * T + t) * H4 + vv]);
    }
}

extern "C" void kernel_launch(void* const* d_in, const int* in_sizes, int n_in,
                              void* d_out, int out_size, void* d_ws, size_t ws_size,
                              hipStream_t stream) {
    const float* ehs = (const float*)d_in[0];
    const int*   dur = (const int*)d_in[1];

    const int T = out_size / (BB * (HH + 1));   // out_size = B*T*(H+1)

    float* out  = (float*)d_out;
    float* mask = (float*)d_out + (size_t)BB * T * HH;

    dim3 grid((T + TT - 1) / TT, BB);
    lenreg_kernel<<<grid, dim3(NT), 0, stream>>>(ehs, dur, out, mask, T);
}